// Round 1
// baseline (1317.260 us; speedup 1.0000x reference)
//
#include <hip/hip_runtime.h>

#define TT 2048
#define BB 64
#define HH 256   // EMB == HID == 256

typedef _Float16 half2_t __attribute__((ext_vector_type(2)));
typedef _Float16 half8_t __attribute__((ext_vector_type(8)));
typedef float f32x4 __attribute__((ext_vector_type(4)));

// ---------------------------------------------------------------------------
// prep: transpose + fp16-convert W_ih and W_hh into [N][K] row-major so that
// MFMA B-fragments / per-column GEMV reads are contiguous in K.
// ---------------------------------------------------------------------------
__global__ void prep_kernel(const float* __restrict__ Wih, const float* __restrict__ Whh,
                            _Float16* __restrict__ WihT, _Float16* __restrict__ WhhT) {
  const int n = blockIdx.x;   // output column
  const int k = threadIdx.x;  // input row
  WihT[n * HH + k] = (_Float16)Wih[k * HH + n];
  WhhT[n * HH + k] = (_Float16)Whh[k * HH + n];
}

// ---------------------------------------------------------------------------
// Part A: U[t][b][n] = (emb[source[b][t]] @ W_ih)[n] + b_ih[n] + b_hh[n], fp16.
// Grid (2048, 4): one WG per (t, 64-wide n-slice). 4 waves x 16 batch rows.
// MFMA f32_16x16x32_f16: A[m=lane&15][k=quad*8+j], B[k][n=lane&15] from
// W^T[n][k] LDS tile (pad to 280 halfs/row: stride 140 dwords -> 2-way max,
// free per m136; 560 B keeps 16B alignment for ds_read_b128).
// C/D: col=lane&15, row=quad*4+reg (m89-verified, dtype-independent).
// ---------------------------------------------------------------------------
__global__ __launch_bounds__(256, 2) void embed_gemm_kernel(
    const int* __restrict__ source, const float* __restrict__ emb,
    const _Float16* __restrict__ WihT, const float* __restrict__ b_ih,
    const float* __restrict__ b_hh, _Float16* __restrict__ U) {
  const int t = blockIdx.x;
  const int nbase = blockIdx.y * 64;
  __shared__ __align__(16) _Float16 Bs[64][280];

  const int tid = threadIdx.x;
  // cooperative load of W^T slice: 64 rows x 256 halfs = 2048 x 16B chunks
  for (int c = tid; c < 64 * 32; c += 256) {
    const int n = c >> 5;
    const int ko = (c & 31) * 8;
    *(half8_t*)&Bs[n][ko] = *(const half8_t*)(WihT + (size_t)(nbase + n) * HH + ko);
  }
  __syncthreads();

  const int lane = tid & 63;
  const int wave = tid >> 6;
  const int row16 = lane & 15;
  const int quad = lane >> 4;
  const int b = wave * 16 + row16;              // A-fragment row = batch
  const int src = source[b * TT + t];           // source is [B][T]
  const float* arow = emb + (size_t)src * HH + quad * 8;

  f32x4 acc[4];
#pragma unroll
  for (int ct = 0; ct < 4; ++ct) acc[ct] = (f32x4){0.f, 0.f, 0.f, 0.f};

#pragma unroll
  for (int kt = 0; kt < 8; ++kt) {
    const float4 x0 = *(const float4*)(arow + kt * 32);
    const float4 x1 = *(const float4*)(arow + kt * 32 + 4);
    half8_t af;
    af[0] = (_Float16)x0.x; af[1] = (_Float16)x0.y;
    af[2] = (_Float16)x0.z; af[3] = (_Float16)x0.w;
    af[4] = (_Float16)x1.x; af[5] = (_Float16)x1.y;
    af[6] = (_Float16)x1.z; af[7] = (_Float16)x1.w;
#pragma unroll
    for (int ct = 0; ct < 4; ++ct) {
      const half8_t bf = *(const half8_t*)&Bs[ct * 16 + row16][quad * 8 + kt * 32];
      acc[ct] = __builtin_amdgcn_mfma_f32_16x16x32_f16(af, bf, acc[ct], 0, 0, 0);
    }
  }

#pragma unroll
  for (int ct = 0; ct < 4; ++ct) {
    const int nn = nbase + ct * 16 + row16;     // C col = lane&15
    const float bias = b_ih[nn] + b_hh[nn];
#pragma unroll
    for (int r = 0; r < 4; ++r) {
      const int bb = wave * 16 + quad * 4 + r;  // C row = quad*4 + reg
      U[((size_t)t * BB + bb) * HH + nn] = (_Float16)(acc[ct][r] + bias);
    }
  }
}

// ---------------------------------------------------------------------------
// Part B: the recurrence. One WG per batch (64 WGs, no cross-WG sync).
// Thread j owns hidden column j; W_hh column j lives in 128 VGPRs (fp16 pairs).
// h broadcast via LDS (uniform-address ds_read_b128, conflict-free); ping-pong
// buffers -> exactly one s_barrier per step. 128 v_dot2_f32_f16 per step per
// thread across 4 independent accumulator chains (hides dep latency).
// ---------------------------------------------------------------------------
__global__ __launch_bounds__(256, 1) void rnn_scan_kernel(
    const _Float16* __restrict__ U, const _Float16* __restrict__ WhhT,
    float* __restrict__ out) {
  const int b = blockIdx.x;
  const int j = threadIdx.x;
  __shared__ __align__(16) _Float16 hbuf[2][HH];

  // preload W_hh column j: 256 fp16 = 32 x 16B
  half8_t w[32];
  const half8_t* wp = (const half8_t*)(WhhT + (size_t)j * HH);
#pragma unroll
  for (int i = 0; i < 32; ++i) w[i] = wp[i];

  hbuf[0][j] = (_Float16)0.f;  // h0 = 0
  const _Float16* Up = U + b * HH + j;
  _Float16 u_next = Up[0];
  float hn = 0.f;
  __syncthreads();

  for (int t = 0; t < TT; ++t) {
    const _Float16 u_cur = u_next;
    // prefetch next step's u (wraps harmlessly at t = TT-1)
    u_next = Up[(size_t)((t + 1) & (TT - 1)) * (BB * HH)];

    const half8_t* hp8 = (const half8_t*)hbuf[t & 1];
    float a0 = (float)u_cur, a1 = 0.f, a2 = 0.f, a3 = 0.f;
#pragma unroll
    for (int i = 0; i < 32; ++i) {
      const half8_t hv = hp8[i];  // broadcast: all lanes same address
      const half8_t wv = w[i];
      a0 = __builtin_amdgcn_fdot2((half2_t){hv[0], hv[1]}, (half2_t){wv[0], wv[1]}, a0, false);
      a1 = __builtin_amdgcn_fdot2((half2_t){hv[2], hv[3]}, (half2_t){wv[2], wv[3]}, a1, false);
      a2 = __builtin_amdgcn_fdot2((half2_t){hv[4], hv[5]}, (half2_t){wv[4], wv[5]}, a2, false);
      a3 = __builtin_amdgcn_fdot2((half2_t){hv[6], hv[7]}, (half2_t){wv[6], wv[7]}, a3, false);
    }
    const float a = (a0 + a1) + (a2 + a3);
    // tanh(a) = 1 - 2/(exp(2a)+1), fp32 via v_exp/v_rcp
    const float e = __builtin_amdgcn_exp2f(a * 2.885390081777927f);  // 2*log2(e)
    hn = 1.f - 2.f * __builtin_amdgcn_rcpf(e + 1.f);

    hbuf[(t + 1) & 1][j] = (_Float16)hn;  // write other buffer: no pre-barrier needed
    __syncthreads();                      // one barrier per step
  }
  out[(size_t)b * HH + j] = hn;
}

// ---------------------------------------------------------------------------
extern "C" void kernel_launch(void* const* d_in, const int* in_sizes, int n_in,
                              void* d_out, int out_size, void* d_ws, size_t ws_size,
                              hipStream_t stream) {
  const int*   source = (const int*)d_in[0];
  const float* emb    = (const float*)d_in[1];
  const float* Wih    = (const float*)d_in[2];
  const float* Whh    = (const float*)d_in[3];
  const float* bih    = (const float*)d_in[4];
  const float* bhh    = (const float*)d_in[5];
  float* out = (float*)d_out;

  char* ws = (char*)d_ws;
  _Float16* U    = (_Float16*)ws;                    // 2048*64*256*2 = 67,108,864 B
  _Float16* WihT = (_Float16*)(ws + 67108864);       // 131,072 B
  _Float16* WhhT = (_Float16*)(ws + 67239936);       // 131,072 B (total 67.4 MB)

  prep_kernel<<<dim3(256), dim3(256), 0, stream>>>(Wih, Whh, WihT, WhhT);
  embed_gemm_kernel<<<dim3(TT, 4), dim3(256), 0, stream>>>(source, emb, WihT, bih, bhh, U);
  rnn_scan_kernel<<<dim3(BB), dim3(256), 0, stream>>>(U, WhhT, out);
}